// Round 14
// baseline (312.187 us; speedup 1.0000x reference)
//
#include <hip/hip_runtime.h>
#include <hip/hip_bf16.h>
#include <stdint.h>

#define N_ENT 100000
#define EDIM 128
#define NHEAD 8
#define FDIM 512
#define NB 512
#define SEQ 12
#define CTXL 5
#define LN_EPS 1e-5f
#define QS 388  // qkvf row stride (floats): 384+4 pad spreads banks
#define RS 132  // rbuf row stride (floats)

typedef __attribute__((ext_vector_type(8))) short bf16x8;
typedef __attribute__((ext_vector_type(4))) float f32x4;
typedef __attribute__((ext_vector_type(16))) float f32x16;

__device__ __forceinline__ short f2bf(float f) {
  __hip_bfloat16 h = __float2bfloat16(f);
  return (short)__bfloat16_as_ushort(h);
}
__device__ __forceinline__ float bf2f(unsigned short u) {
  union { uint32_t i; float f; } x; x.i = ((uint32_t)u) << 16; return x.f;
}

// swizzled byte addr inside bf16 LDS tiles (16B chunks XOR row&7)
__device__ __forceinline__ int XADDR(int row, int k) {  // stride 256B (128 bf16)
  return row * 256 + ((((k) >> 3) ^ (row & 7)) << 4) + ((k) & 7) * 2;
}
__device__ __forceinline__ int AADDR(int row, int k) {  // stride 1024B (512 bf16)
  return row * 1024 + ((((k) >> 3) ^ (row & 7)) << 4) + ((k) & 7) * 2;
}

// ---- weights -> bf16, native [out][in] layouts, per-layer contiguous ----
#define LSTRIDE 196608
__global__ void wbf_kernel(const float* __restrict__ Wqkv,
                           const float* __restrict__ Wo,
                           const float* __restrict__ W1,
                           const float* __restrict__ W2,
                           short* __restrict__ Wbf) {
  int idx = blockIdx.x * 256 + threadIdx.x;  // 0..393215
  int layer = idx / LSTRIDE;
  int r = idx % LSTRIDE;
  float v;
  if (r < 49152) v = Wqkv[layer * 49152 + r];
  else if (r < 65536) v = Wo[layer * 16384 + (r - 49152)];
  else if (r < 131072) v = W1[layer * 65536 + (r - 65536)];
  else v = W2[layer * 65536 + (r - 131072)];
  Wbf[idx] = f2bf(v);
}

// ------- fused MFMA encoder: gather -> 2 layers -> prep (Abfs + hist) ------
// Identical to round 13 (frozen for attribution).
__global__ __launch_bounds__(256, 2) void encoder_fused(
    const int* __restrict__ inp, const int* __restrict__ nextCheckin,
    const float* __restrict__ ctxSub, const float* __restrict__ ent,
    const float* __restrict__ ent_t, const float* __restrict__ rel,
    const float* __restrict__ rel_inv, const float* __restrict__ ctx,
    const short* __restrict__ Wbf, const float* __restrict__ bqkv_,
    const float* __restrict__ bo_, const float* __restrict__ b1_,
    const float* __restrict__ b2_, const float* __restrict__ g1_,
    const float* __restrict__ be1_, const float* __restrict__ g2_,
    const float* __restrict__ be2_, short* __restrict__ Abfs,
    float* __restrict__ hist) {
  __shared__ char lds[39104];
  char* xbuf = lds;                      // [16][128] bf16 swz   4KB
  char* abuf = lds + 4096;               // [16][512] bf16 swz  16KB
  float* qkvf = (float*)(lds + 20480);   // [12][388] fp32      18.2KB
  float* rbuf = (float*)(lds + 20480);   // [12][132] fp32 (reuse)

  int m = blockIdx.x;
  int tid = threadIdx.x;
  int wave = tid >> 6, lane = tid & 63;
  int q = lane >> 4, lr = lane & 15;

  // ---- gather -> xbuf bf16 (swizzled); zero pad rows 12..15 ----
  {
    for (int i = tid; i < 256; i += 256) ((uint32_t*)(xbuf + 12 * 256))[i] = 0;
    for (int i = tid; i < 1024; i += 256) ((uint32_t*)(abuf + 12 * 1024))[i] = 0;
    if (tid < EDIM) {
      int e = tid;
      int i0 = inp[0 * NB + m], i1 = inp[1 * NB + m], i2 = inp[2 * NB + m];
      *(unsigned short*)(xbuf + XADDR(0, e)) = (unsigned short)f2bf(ent[(size_t)i0 * EDIM + e]);
      *(unsigned short*)(xbuf + XADDR(1, e)) = (unsigned short)f2bf(ent_t[(size_t)i0 * EDIM + e]);
      *(unsigned short*)(xbuf + XADDR(2, e)) = (unsigned short)f2bf(rel[(size_t)i1 * EDIM + e]);
      *(unsigned short*)(xbuf + XADDR(3, e)) = (unsigned short)f2bf(rel_inv[(size_t)i1 * EDIM + e]);
      *(unsigned short*)(xbuf + XADDR(4, e)) = (unsigned short)f2bf(ent[(size_t)i2 * EDIM + e]);
      *(unsigned short*)(xbuf + XADDR(5, e)) = (unsigned short)f2bf(ent_t[(size_t)i2 * EDIM + e]);
#pragma unroll
      for (int j = 0; j < CTXL; ++j) {
        int c = inp[(3 + j) * NB + m];
        *(unsigned short*)(xbuf + XADDR(6 + j, e)) = (unsigned short)f2bf(ctx[(size_t)c * EDIM + e]);
      }
      *(unsigned short*)(xbuf + XADDR(11, e)) = (unsigned short)f2bf(ctxSub[(size_t)m * EDIM + e]);
    }
  }
  __syncthreads();

  for (int l = 0; l < 2; ++l) {
    const short* Wq = Wbf + (size_t)l * LSTRIDE;
    const short* Wo = Wq + 49152;
    const short* W1 = Wq + 65536;
    const short* W2 = Wq + 131072;
    const float* bqkv = bqkv_ + l * 384;
    const float* bo = bo_ + l * 128;
    const float* b1 = b1_ + l * 512;
    const float* b2 = b2_ + l * 128;
    const float* g1 = g1_ + l * 128;
    const float* be1 = be1_ + l * 128;
    const float* g2 = g2_ + l * 128;
    const float* be2 = be2_ + l * 128;

    // ---------- qkv GEMM ----------
    {
      bf16x8 a[4];
#pragma unroll
      for (int ks = 0; ks < 4; ++ks)
        a[ks] = *(const bf16x8*)(xbuf + XADDR(lr, ks * 32 + q * 8));
      int tbase = q * 4;
      for (int nt = wave; nt < 24; nt += 4) {
        const short* wr = Wq + (nt * 16 + lr) * 128;
        bf16x8 bq[4];
#pragma unroll
        for (int ks = 0; ks < 4; ++ks) bq[ks] = *(const bf16x8*)(wr + ks * 32 + q * 8);
        float bias = bqkv[nt * 16 + lr];
        f32x4 acc{};
#pragma unroll
        for (int ks = 0; ks < 4; ++ks)
          acc = __builtin_amdgcn_mfma_f32_16x16x32_bf16(a[ks], bq[ks], acc, 0, 0, 0);
        if (tbase < 12) {
#pragma unroll
          for (int r = 0; r < 4; ++r)
            qkvf[(tbase + r) * QS + nt * 16 + lr] = acc[r] + bias;
        }
      }
    }
    __syncthreads();

    // ---------- attention ----------
    if (tid < 96) {
      int h = tid & 7, tq = tid >> 3;
      const float scale = 0.25f;
      float s[SEQ];
      float mx = -1e30f;
#pragma unroll
      for (int tk = 0; tk < SEQ; ++tk) {
        float d = 0.f;
#pragma unroll
        for (int dd = 0; dd < 16; ++dd)
          d += qkvf[tq * QS + h * 16 + dd] * qkvf[tk * QS + 128 + h * 16 + dd];
        s[tk] = d * scale;
        mx = fmaxf(mx, s[tk]);
      }
      float sum = 0.f;
#pragma unroll
      for (int tk = 0; tk < SEQ; ++tk) { s[tk] = __expf(s[tk] - mx); sum += s[tk]; }
      float inv = 1.0f / sum;
#pragma unroll
      for (int dd = 0; dd < 16; dd += 2) {
        float o0 = 0.f, o1 = 0.f;
#pragma unroll
        for (int tk = 0; tk < SEQ; ++tk) {
          o0 += s[tk] * qkvf[tk * QS + 256 + h * 16 + dd];
          o1 += s[tk] * qkvf[tk * QS + 256 + h * 16 + dd + 1];
        }
        uint32_t pk = (uint32_t)(unsigned short)f2bf(o0 * inv) |
                      ((uint32_t)(unsigned short)f2bf(o1 * inv) << 16);
        *(uint32_t*)(abuf + AADDR(tq, h * 16 + dd)) = pk;
      }
    }
    __syncthreads();

    // ---------- out-proj GEMM + residual -> rbuf ----------
    {
      bf16x8 a[4];
#pragma unroll
      for (int ks = 0; ks < 4; ++ks)
        a[ks] = *(const bf16x8*)(abuf + AADDR(lr, ks * 32 + q * 8));
      int tbase = q * 4;
      for (int nt = wave; nt < 8; nt += 4) {
        const short* wr = Wo + (nt * 16 + lr) * 128;
        bf16x8 bq[4];
#pragma unroll
        for (int ks = 0; ks < 4; ++ks) bq[ks] = *(const bf16x8*)(wr + ks * 32 + q * 8);
        float bias = bo[nt * 16 + lr];
        f32x4 acc{};
#pragma unroll
        for (int ks = 0; ks < 4; ++ks)
          acc = __builtin_amdgcn_mfma_f32_16x16x32_bf16(a[ks], bq[ks], acc, 0, 0, 0);
        if (tbase < 12) {
          int e = nt * 16 + lr;
#pragma unroll
          for (int r = 0; r < 4; ++r) {
            int t = tbase + r;
            float res = bf2f(*(const unsigned short*)(xbuf + XADDR(t, e)));
            rbuf[t * RS + e] = acc[r] + bias + res;
          }
        }
      }
    }
    __syncthreads();

    // ---------- LN1 ----------
    {
      for (int row = wave; row < SEQ; row += 4) {
        float v0 = rbuf[row * RS + 2 * lane], v1 = rbuf[row * RS + 2 * lane + 1];
        float sum = v0 + v1, sq = v0 * v0 + v1 * v1;
#pragma unroll
        for (int off = 32; off; off >>= 1) { sum += __shfl_xor(sum, off); sq += __shfl_xor(sq, off); }
        float mu = sum * (1.0f / 128.0f);
        float var = sq * (1.0f / 128.0f) - mu * mu;
        float rs = rsqrtf(var + LN_EPS);
        float y0 = (v0 - mu) * rs * g1[2 * lane] + be1[2 * lane];
        float y1 = (v1 - mu) * rs * g1[2 * lane + 1] + be1[2 * lane + 1];
        uint32_t pk = (uint32_t)(unsigned short)f2bf(y0) |
                      ((uint32_t)(unsigned short)f2bf(y1) << 16);
        *(uint32_t*)(xbuf + XADDR(row, 2 * lane)) = pk;
      }
    }
    __syncthreads();

    // ---------- FFN1 GEMM + relu -> abuf ----------
    {
      bf16x8 a[4];
#pragma unroll
      for (int ks = 0; ks < 4; ++ks)
        a[ks] = *(const bf16x8*)(xbuf + XADDR(lr, ks * 32 + q * 8));
      int tbase = q * 4;
      for (int nt = wave; nt < 32; nt += 4) {
        const short* wr = W1 + (nt * 16 + lr) * 128;
        bf16x8 bq[4];
#pragma unroll
        for (int ks = 0; ks < 4; ++ks) bq[ks] = *(const bf16x8*)(wr + ks * 32 + q * 8);
        float bias = b1[nt * 16 + lr];
        f32x4 acc{};
#pragma unroll
        for (int ks = 0; ks < 4; ++ks)
          acc = __builtin_amdgcn_mfma_f32_16x16x32_bf16(a[ks], bq[ks], acc, 0, 0, 0);
        if (tbase < 12) {
          int f = nt * 16 + lr;
#pragma unroll
          for (int r = 0; r < 4; ++r) {
            float h = fmaxf(acc[r] + bias, 0.0f);
            *(unsigned short*)(abuf + AADDR(tbase + r, f)) = (unsigned short)f2bf(h);
          }
        }
      }
    }
    __syncthreads();

    // ---------- FFN2 GEMM (K=512) + residual -> rbuf ----------
    {
      bf16x8 a2[16];
#pragma unroll
      for (int ks = 0; ks < 16; ++ks)
        a2[ks] = *(const bf16x8*)(abuf + AADDR(lr, ks * 32 + q * 8));
      int tbase = q * 4;
      for (int nt = wave; nt < 8; nt += 4) {
        const short* wr = W2 + (nt * 16 + lr) * 512;
        float bias = b2[nt * 16 + lr];
        f32x4 acc{};
#pragma unroll
        for (int ks = 0; ks < 16; ++ks) {
          bf16x8 bq = *(const bf16x8*)(wr + ks * 32 + q * 8);
          acc = __builtin_amdgcn_mfma_f32_16x16x32_bf16(a2[ks], bq, acc, 0, 0, 0);
        }
        if (tbase < 12) {
          int e = nt * 16 + lr;
#pragma unroll
          for (int r = 0; r < 4; ++r) {
            int t = tbase + r;
            float res = bf2f(*(const unsigned short*)(xbuf + XADDR(t, e)));
            rbuf[t * RS + e] = acc[r] + bias + res;
          }
        }
      }
    }
    __syncthreads();

    // ---------- LN2 ----------
    {
      for (int row = wave; row < SEQ; row += 4) {
        float v0 = rbuf[row * RS + 2 * lane], v1 = rbuf[row * RS + 2 * lane + 1];
        float sum = v0 + v1, sq = v0 * v0 + v1 * v1;
#pragma unroll
        for (int off = 32; off; off >>= 1) { sum += __shfl_xor(sum, off); sq += __shfl_xor(sq, off); }
        float mu = sum * (1.0f / 128.0f);
        float var = sq * (1.0f / 128.0f) - mu * mu;
        float rs = rsqrtf(var + LN_EPS);
        float y0 = (v0 - mu) * rs * g2[2 * lane] + be2[2 * lane];
        float y1 = (v1 - mu) * rs * g2[2 * lane + 1] + be2[2 * lane + 1];
        uint32_t pk = (uint32_t)(unsigned short)f2bf(y0) |
                      ((uint32_t)(unsigned short)f2bf(y1) << 16);
        *(uint32_t*)(xbuf + XADDR(row, 2 * lane)) = pk;
        rbuf[row * RS + 2 * lane] = y0;
        rbuf[row * RS + 2 * lane + 1] = y1;
      }
    }
    __syncthreads();
  }

  // ---- prep epilogue: FRAGMENT-MAJOR Abfs + hist ----
  if (tid < EDIM) {
    int e = tid;
    int r = nextCheckin[NB + m];
    float a0 = rbuf[0 * RS + e] * rel[(size_t)r * EDIM + e];
    float a1 = rbuf[1 * RS + e] * rel_inv[(size_t)r * EDIM + e];
    int mc = m >> 6, mhalf = (m >> 5) & 1, l31 = m & 31;
    int kh = (e >> 3) & 1, j = e & 7;
    int ks0 = e >> 4, ks1 = 8 + (e >> 4);
    size_t base = (size_t)mc * 16384 + (kh * 32 + l31) * 8 + j;
    Abfs[base + (ks0 * 2 + mhalf) * 512] = f2bf(a0);
    Abfs[base + (ks1 * 2 + mhalf) * 512] = f2bf(a1);
    hist[(size_t)m * EDIM + e] = rbuf[11 * RS + e];
  }
}

// ---------------- scores: identical to round 13 ----------------------------
__global__ __launch_bounds__(256, 3) void score_kernel(
    const short* __restrict__ Abfs, const float* __restrict__ ent,
    const float* __restrict__ ent_t, float* __restrict__ out) {
  __shared__ char lds[32768];  // B strip only

  int tid = threadIdx.x;
  int wave = tid >> 6;
  int lane = tid & 63;
  int nbase = blockIdx.x * 64;

#pragma unroll
  for (int i = 0; i < 16; ++i) {
    int flat = i * 256 + tid;
    int row = flat >> 6;
    int c4 = flat & 63;
    int n = nbase + row;
    float4 v = make_float4(0.f, 0.f, 0.f, 0.f);
    if (n < N_ENT) {
      const float* src = (c4 < 32) ? ent + (size_t)n * 128 + c4 * 4
                                   : ent_t + (size_t)n * 128 + (c4 - 32) * 4;
      v = *(const float4*)src;
    }
    short4 bb;
    bb.x = f2bf(v.x); bb.y = f2bf(v.y); bb.z = f2bf(v.z); bb.w = f2bf(v.w);
    int chunk = c4 >> 1, half = c4 & 1;
    *(short4*)(lds + row * 512 + ((chunk ^ (row & 7)) << 4) + half * 8) = bb;
  }
  __syncthreads();  // B visible (the only barrier)

  int l31 = lane & 31, kh = lane >> 5;
  int nhalf = wave >> 1, mhalf = wave & 1;
  int brow = nhalf * 32 + l31;
  int col = nbase + nhalf * 32 + l31;
  bool cvalid = (col < N_ENT);

  bf16x8 bfr[16];
#pragma unroll
  for (int ks = 0; ks < 16; ++ks) {
    int c = ks * 2 + kh;
    bfr[ks] = *(const bf16x8*)(lds + brow * 512 + ((c ^ (brow & 7)) << 4));
  }

  const char* gA = (const char*)Abfs;

  for (int mc = 0; mc < 8; ++mc) {
    const char* base = gA + (size_t)mc * 32768 + mhalf * 1024 + lane * 16;
    f32x16 acc{};
    bf16x8 af[8];
#pragma unroll
    for (int ks = 0; ks < 8; ++ks) af[ks] = *(const bf16x8*)(base + ks * 2048);
#pragma unroll
    for (int ks = 0; ks < 8; ++ks)
      acc = __builtin_amdgcn_mfma_f32_32x32x16_bf16(af[ks], bfr[ks], acc, 0, 0, 0);
#pragma unroll
    for (int ks = 0; ks < 8; ++ks) af[ks] = *(const bf16x8*)(base + (8 + ks) * 2048);
#pragma unroll
    for (int ks = 0; ks < 8; ++ks)
      acc = __builtin_amdgcn_mfma_f32_32x32x16_bf16(af[ks], bfr[8 + ks], acc, 0, 0, 0);

    if (cvalid) {
#pragma unroll
      for (int r = 0; r < 16; ++r) {
        int row = mc * 64 + mhalf * 32 + (r & 3) + 8 * (r >> 2) + 4 * kh;
        float v = fminf(fmaxf(acc[r] * 0.5f, -20.0f), 20.0f);
        out[(size_t)row * N_ENT + col] = v;
      }
    }
  }
}

extern "C" void kernel_launch(void* const* d_in, const int* in_sizes, int n_in,
                              void* d_out, int out_size, void* d_ws,
                              size_t ws_size, hipStream_t stream) {
  const int* inp = (const int*)d_in[0];
  const int* nextCheckin = (const int*)d_in[1];
  const float* ctxSub = (const float*)d_in[2];
  const float* ent = (const float*)d_in[3];
  const float* ent_t = (const float*)d_in[4];
  const float* rel = (const float*)d_in[5];
  const float* rel_inv = (const float*)d_in[6];
  const float* ctx = (const float*)d_in[7];
  const float* Wqkv = (const float*)d_in[8];
  const float* bqkv = (const float*)d_in[9];
  const float* Wo = (const float*)d_in[10];
  const float* bo = (const float*)d_in[11];
  const float* W1 = (const float*)d_in[12];
  const float* b1 = (const float*)d_in[13];
  const float* W2 = (const float*)d_in[14];
  const float* b2 = (const float*)d_in[15];
  const float* g1 = (const float*)d_in[16];
  const float* be1 = (const float*)d_in[17];
  const float* g2 = (const float*)d_in[18];
  const float* be2 = (const float*)d_in[19];
  float* out = (float*)d_out;

  short* Abfs = (short*)d_ws;                         // 256 KB (fragment-major)
  short* Wbf = (short*)((char*)d_ws + 262144);        // 768 KB bf16 weights
  float* hist = out + (size_t)NB * N_ENT;

  wbf_kernel<<<1536, 256, 0, stream>>>(Wqkv, Wo, W1, W2, Wbf);
  encoder_fused<<<NB, 256, 0, stream>>>(
      inp, nextCheckin, ctxSub, ent, ent_t, rel, rel_inv, ctx, Wbf, bqkv, bo,
      b1, b2, g1, be1, g2, be2, Abfs, hist);
  // MEASUREMENT: score launched 3x (idempotent writes). total = base + 2*score.
  score_kernel<<<1563, 256, 0, stream>>>(Abfs, ent, ent_t, out);
  score_kernel<<<1563, 256, 0, stream>>>(Abfs, ent, ent_t, out);
  score_kernel<<<1563, 256, 0, stream>>>(Abfs, ent, ent_t, out);
}

// Round 15
// 179.976 us; speedup vs baseline: 1.7346x; 1.7346x over previous
//
#include <hip/hip_runtime.h>
#include <hip/hip_bf16.h>
#include <stdint.h>

#define N_ENT 100000
#define EDIM 128
#define NHEAD 8
#define FDIM 512
#define NB 512
#define SEQ 12
#define CTXL 5
#define LN_EPS 1e-5f
#define QS 388  // qkvf row stride (floats): 384+4 pad spreads banks
#define RS 132  // rbuf row stride (floats)

typedef __attribute__((ext_vector_type(8))) short bf16x8;
typedef __attribute__((ext_vector_type(4))) float f32x4;
typedef __attribute__((ext_vector_type(16))) float f32x16;

__device__ __forceinline__ short f2bf(float f) {
  __hip_bfloat16 h = __float2bfloat16(f);
  return (short)__bfloat16_as_ushort(h);
}
__device__ __forceinline__ float bf2f(unsigned short u) {
  union { uint32_t i; float f; } x; x.i = ((uint32_t)u) << 16; return x.f;
}

// swizzled byte addr inside bf16 LDS tiles (16B chunks XOR row&7)
__device__ __forceinline__ int XADDR(int row, int k) {  // stride 256B (128 bf16)
  return row * 256 + ((((k) >> 3) ^ (row & 7)) << 4) + ((k) & 7) * 2;
}
__device__ __forceinline__ int AADDR(int row, int k) {  // stride 1024B (512 bf16)
  return row * 1024 + ((((k) >> 3) ^ (row & 7)) << 4) + ((k) & 7) * 2;
}

// ---- weights -> bf16 FRAGMENT-MAJOR layout ----
// Per layer (LSTRIDE shorts): qkv frags @0 (nt24,ks4) | Wo @49152 (nt8,ks4) |
// W1 @65536 (nt32,ks4) | W2 @131072 (nt8,ks16). Fragment (nt,ks) is 512
// shorts: lane-major (lane=q*16+lr, 8 shorts each). Encoder reads each frag
// as wave-uniform base + lane*16B -> one coalesced 1KB L2 burst.
#define LSTRIDE 196608
__global__ void wbf_kernel(const float* __restrict__ Wqkv,
                           const float* __restrict__ Wo,
                           const float* __restrict__ W1,
                           const float* __restrict__ W2,
                           short* __restrict__ Wbf) {
  int idx = blockIdx.x * 256 + threadIdx.x;  // 0..393215
  int layer = idx / LSTRIDE;
  int r = idx % LSTRIDE;
  float v;
  if (r < 49152) {
    int rr = r; int fid = rr >> 9; int w = rr & 511;
    int lane = w >> 3, j = w & 7, nt = fid >> 2, ks = fid & 3;
    int lr = lane & 15, q = lane >> 4;
    v = Wqkv[layer * 49152 + (nt * 16 + lr) * 128 + ks * 32 + q * 8 + j];
  } else if (r < 65536) {
    int rr = r - 49152; int fid = rr >> 9; int w = rr & 511;
    int lane = w >> 3, j = w & 7, nt = fid >> 2, ks = fid & 3;
    int lr = lane & 15, q = lane >> 4;
    v = Wo[layer * 16384 + (nt * 16 + lr) * 128 + ks * 32 + q * 8 + j];
  } else if (r < 131072) {
    int rr = r - 65536; int fid = rr >> 9; int w = rr & 511;
    int lane = w >> 3, j = w & 7, nt = fid >> 2, ks = fid & 3;
    int lr = lane & 15, q = lane >> 4;
    v = W1[layer * 65536 + (nt * 16 + lr) * 128 + ks * 32 + q * 8 + j];
  } else {
    int rr = r - 131072; int fid = rr >> 9; int w = rr & 511;
    int lane = w >> 3, j = w & 7, nt = fid >> 4, ks = fid & 15;
    int lr = lane & 15, q = lane >> 4;
    v = W2[layer * 65536 + (nt * 16 + lr) * 512 + ks * 32 + q * 8 + j];
  }
  Wbf[idx] = f2bf(v);
}

// ------- fused MFMA encoder: gather -> 2 layers -> prep (Abfs + hist) ------
// Same structure as round 13; only the weight-fragment addressing changed
// (fragment-major coalesced reads).
__global__ __launch_bounds__(256, 2) void encoder_fused(
    const int* __restrict__ inp, const int* __restrict__ nextCheckin,
    const float* __restrict__ ctxSub, const float* __restrict__ ent,
    const float* __restrict__ ent_t, const float* __restrict__ rel,
    const float* __restrict__ rel_inv, const float* __restrict__ ctx,
    const short* __restrict__ Wbf, const float* __restrict__ bqkv_,
    const float* __restrict__ bo_, const float* __restrict__ b1_,
    const float* __restrict__ b2_, const float* __restrict__ g1_,
    const float* __restrict__ be1_, const float* __restrict__ g2_,
    const float* __restrict__ be2_, short* __restrict__ Abfs,
    float* __restrict__ hist) {
  __shared__ char lds[39104];
  char* xbuf = lds;                      // [16][128] bf16 swz   4KB
  char* abuf = lds + 4096;               // [16][512] bf16 swz  16KB
  float* qkvf = (float*)(lds + 20480);   // [12][388] fp32      18.2KB
  float* rbuf = (float*)(lds + 20480);   // [12][132] fp32 (reuse)

  int m = blockIdx.x;
  int tid = threadIdx.x;
  int wave = tid >> 6, lane = tid & 63;
  int q = lane >> 4, lr = lane & 15;

  // ---- gather -> xbuf bf16 (swizzled); zero pad rows 12..15 ----
  {
    for (int i = tid; i < 256; i += 256) ((uint32_t*)(xbuf + 12 * 256))[i] = 0;
    for (int i = tid; i < 1024; i += 256) ((uint32_t*)(abuf + 12 * 1024))[i] = 0;
    if (tid < EDIM) {
      int e = tid;
      int i0 = inp[0 * NB + m], i1 = inp[1 * NB + m], i2 = inp[2 * NB + m];
      *(unsigned short*)(xbuf + XADDR(0, e)) = (unsigned short)f2bf(ent[(size_t)i0 * EDIM + e]);
      *(unsigned short*)(xbuf + XADDR(1, e)) = (unsigned short)f2bf(ent_t[(size_t)i0 * EDIM + e]);
      *(unsigned short*)(xbuf + XADDR(2, e)) = (unsigned short)f2bf(rel[(size_t)i1 * EDIM + e]);
      *(unsigned short*)(xbuf + XADDR(3, e)) = (unsigned short)f2bf(rel_inv[(size_t)i1 * EDIM + e]);
      *(unsigned short*)(xbuf + XADDR(4, e)) = (unsigned short)f2bf(ent[(size_t)i2 * EDIM + e]);
      *(unsigned short*)(xbuf + XADDR(5, e)) = (unsigned short)f2bf(ent_t[(size_t)i2 * EDIM + e]);
#pragma unroll
      for (int j = 0; j < CTXL; ++j) {
        int c = inp[(3 + j) * NB + m];
        *(unsigned short*)(xbuf + XADDR(6 + j, e)) = (unsigned short)f2bf(ctx[(size_t)c * EDIM + e]);
      }
      *(unsigned short*)(xbuf + XADDR(11, e)) = (unsigned short)f2bf(ctxSub[(size_t)m * EDIM + e]);
    }
  }
  __syncthreads();

  for (int l = 0; l < 2; ++l) {
    const short* Wq = Wbf + (size_t)l * LSTRIDE;
    const short* Wo = Wq + 49152;
    const short* W1 = Wq + 65536;
    const short* W2 = Wq + 131072;
    const float* bqkv = bqkv_ + l * 384;
    const float* bo = bo_ + l * 128;
    const float* b1 = b1_ + l * 512;
    const float* b2 = b2_ + l * 128;
    const float* g1 = g1_ + l * 128;
    const float* be1 = be1_ + l * 128;
    const float* g2 = g2_ + l * 128;
    const float* be2 = be2_ + l * 128;

    // ---------- qkv GEMM: fragment-major weight reads ----------
    {
      bf16x8 a[4];
#pragma unroll
      for (int ks = 0; ks < 4; ++ks)
        a[ks] = *(const bf16x8*)(xbuf + XADDR(lr, ks * 32 + q * 8));
      int tbase = q * 4;
      for (int nt = wave; nt < 24; nt += 4) {
        bf16x8 bq[4];
#pragma unroll
        for (int ks = 0; ks < 4; ++ks)
          bq[ks] = *(const bf16x8*)(Wq + (nt * 4 + ks) * 512 + lane * 8);
        float bias = bqkv[nt * 16 + lr];
        f32x4 acc{};
#pragma unroll
        for (int ks = 0; ks < 4; ++ks)
          acc = __builtin_amdgcn_mfma_f32_16x16x32_bf16(a[ks], bq[ks], acc, 0, 0, 0);
        if (tbase < 12) {
#pragma unroll
          for (int r = 0; r < 4; ++r)
            qkvf[(tbase + r) * QS + nt * 16 + lr] = acc[r] + bias;
        }
      }
    }
    __syncthreads();

    // ---------- attention (96 threads, fp32 from qkvf) ----------
    if (tid < 96) {
      int h = tid & 7, tq = tid >> 3;
      const float scale = 0.25f;
      float s[SEQ];
      float mx = -1e30f;
#pragma unroll
      for (int tk = 0; tk < SEQ; ++tk) {
        float d = 0.f;
#pragma unroll
        for (int dd = 0; dd < 16; ++dd)
          d += qkvf[tq * QS + h * 16 + dd] * qkvf[tk * QS + 128 + h * 16 + dd];
        s[tk] = d * scale;
        mx = fmaxf(mx, s[tk]);
      }
      float sum = 0.f;
#pragma unroll
      for (int tk = 0; tk < SEQ; ++tk) { s[tk] = __expf(s[tk] - mx); sum += s[tk]; }
      float inv = 1.0f / sum;
#pragma unroll
      for (int dd = 0; dd < 16; dd += 2) {
        float o0 = 0.f, o1 = 0.f;
#pragma unroll
        for (int tk = 0; tk < SEQ; ++tk) {
          o0 += s[tk] * qkvf[tk * QS + 256 + h * 16 + dd];
          o1 += s[tk] * qkvf[tk * QS + 256 + h * 16 + dd + 1];
        }
        uint32_t pk = (uint32_t)(unsigned short)f2bf(o0 * inv) |
                      ((uint32_t)(unsigned short)f2bf(o1 * inv) << 16);
        *(uint32_t*)(abuf + AADDR(tq, h * 16 + dd)) = pk;
      }
    }
    __syncthreads();

    // ---------- out-proj GEMM + residual -> rbuf ----------
    {
      bf16x8 a[4];
#pragma unroll
      for (int ks = 0; ks < 4; ++ks)
        a[ks] = *(const bf16x8*)(abuf + AADDR(lr, ks * 32 + q * 8));
      int tbase = q * 4;
      for (int nt = wave; nt < 8; nt += 4) {
        bf16x8 bq[4];
#pragma unroll
        for (int ks = 0; ks < 4; ++ks)
          bq[ks] = *(const bf16x8*)(Wo + (nt * 4 + ks) * 512 + lane * 8);
        float bias = bo[nt * 16 + lr];
        f32x4 acc{};
#pragma unroll
        for (int ks = 0; ks < 4; ++ks)
          acc = __builtin_amdgcn_mfma_f32_16x16x32_bf16(a[ks], bq[ks], acc, 0, 0, 0);
        if (tbase < 12) {
          int e = nt * 16 + lr;
#pragma unroll
          for (int r = 0; r < 4; ++r) {
            int t = tbase + r;
            float res = bf2f(*(const unsigned short*)(xbuf + XADDR(t, e)));
            rbuf[t * RS + e] = acc[r] + bias + res;
          }
        }
      }
    }
    __syncthreads();

    // ---------- LN1 ----------
    {
      for (int row = wave; row < SEQ; row += 4) {
        float v0 = rbuf[row * RS + 2 * lane], v1 = rbuf[row * RS + 2 * lane + 1];
        float sum = v0 + v1, sq = v0 * v0 + v1 * v1;
#pragma unroll
        for (int off = 32; off; off >>= 1) { sum += __shfl_xor(sum, off); sq += __shfl_xor(sq, off); }
        float mu = sum * (1.0f / 128.0f);
        float var = sq * (1.0f / 128.0f) - mu * mu;
        float rs = rsqrtf(var + LN_EPS);
        float y0 = (v0 - mu) * rs * g1[2 * lane] + be1[2 * lane];
        float y1 = (v1 - mu) * rs * g1[2 * lane + 1] + be1[2 * lane + 1];
        uint32_t pk = (uint32_t)(unsigned short)f2bf(y0) |
                      ((uint32_t)(unsigned short)f2bf(y1) << 16);
        *(uint32_t*)(xbuf + XADDR(row, 2 * lane)) = pk;
      }
    }
    __syncthreads();

    // ---------- FFN1 GEMM + relu -> abuf ----------
    {
      bf16x8 a[4];
#pragma unroll
      for (int ks = 0; ks < 4; ++ks)
        a[ks] = *(const bf16x8*)(xbuf + XADDR(lr, ks * 32 + q * 8));
      int tbase = q * 4;
      for (int nt = wave; nt < 32; nt += 4) {
        bf16x8 bq[4];
#pragma unroll
        for (int ks = 0; ks < 4; ++ks)
          bq[ks] = *(const bf16x8*)(W1 + (nt * 4 + ks) * 512 + lane * 8);
        float bias = b1[nt * 16 + lr];
        f32x4 acc{};
#pragma unroll
        for (int ks = 0; ks < 4; ++ks)
          acc = __builtin_amdgcn_mfma_f32_16x16x32_bf16(a[ks], bq[ks], acc, 0, 0, 0);
        if (tbase < 12) {
          int f = nt * 16 + lr;
#pragma unroll
          for (int r = 0; r < 4; ++r) {
            float h = fmaxf(acc[r] + bias, 0.0f);
            *(unsigned short*)(abuf + AADDR(tbase + r, f)) = (unsigned short)f2bf(h);
          }
        }
      }
    }
    __syncthreads();

    // ---------- FFN2 GEMM (K=512) + residual -> rbuf ----------
    {
      bf16x8 a2[16];
#pragma unroll
      for (int ks = 0; ks < 16; ++ks)
        a2[ks] = *(const bf16x8*)(abuf + AADDR(lr, ks * 32 + q * 8));
      int tbase = q * 4;
      for (int nt = wave; nt < 8; nt += 4) {
        float bias = b2[nt * 16 + lr];
        f32x4 acc{};
#pragma unroll
        for (int ks = 0; ks < 16; ++ks) {
          bf16x8 bq = *(const bf16x8*)(W2 + (nt * 16 + ks) * 512 + lane * 8);
          acc = __builtin_amdgcn_mfma_f32_16x16x32_bf16(a2[ks], bq, acc, 0, 0, 0);
        }
        if (tbase < 12) {
          int e = nt * 16 + lr;
#pragma unroll
          for (int r = 0; r < 4; ++r) {
            int t = tbase + r;
            float res = bf2f(*(const unsigned short*)(xbuf + XADDR(t, e)));
            rbuf[t * RS + e] = acc[r] + bias + res;
          }
        }
      }
    }
    __syncthreads();

    // ---------- LN2 ----------
    {
      for (int row = wave; row < SEQ; row += 4) {
        float v0 = rbuf[row * RS + 2 * lane], v1 = rbuf[row * RS + 2 * lane + 1];
        float sum = v0 + v1, sq = v0 * v0 + v1 * v1;
#pragma unroll
        for (int off = 32; off; off >>= 1) { sum += __shfl_xor(sum, off); sq += __shfl_xor(sq, off); }
        float mu = sum * (1.0f / 128.0f);
        float var = sq * (1.0f / 128.0f) - mu * mu;
        float rs = rsqrtf(var + LN_EPS);
        float y0 = (v0 - mu) * rs * g2[2 * lane] + be2[2 * lane];
        float y1 = (v1 - mu) * rs * g2[2 * lane + 1] + be2[2 * lane + 1];
        uint32_t pk = (uint32_t)(unsigned short)f2bf(y0) |
                      ((uint32_t)(unsigned short)f2bf(y1) << 16);
        *(uint32_t*)(xbuf + XADDR(row, 2 * lane)) = pk;
        rbuf[row * RS + 2 * lane] = y0;
        rbuf[row * RS + 2 * lane + 1] = y1;
      }
    }
    __syncthreads();
  }

  // ---- prep epilogue: FRAGMENT-MAJOR Abfs + hist ----
  if (tid < EDIM) {
    int e = tid;
    int r = nextCheckin[NB + m];
    float a0 = rbuf[0 * RS + e] * rel[(size_t)r * EDIM + e];
    float a1 = rbuf[1 * RS + e] * rel_inv[(size_t)r * EDIM + e];
    int mc = m >> 6, mhalf = (m >> 5) & 1, l31 = m & 31;
    int kh = (e >> 3) & 1, j = e & 7;
    int ks0 = e >> 4, ks1 = 8 + (e >> 4);
    size_t base = (size_t)mc * 16384 + (kh * 32 + l31) * 8 + j;
    Abfs[base + (ks0 * 2 + mhalf) * 512] = f2bf(a0);
    Abfs[base + (ks1 * 2 + mhalf) * 512] = f2bf(a1);
    hist[(size_t)m * EDIM + e] = rbuf[11 * RS + e];
  }
}

// ---------------- scores: 128-col strips, barrier-free 32x32 MFMA ----------
// M=512 N=100000 K=256. 782 blocks, one per 128-col strip: tests the DRAM
// write-granularity theory (512B concurrent segments/row vs 256B before).
// B staged once (128 ents, 64KB swizzled LDS) -> bfr[16] in VGPRs; zero
// barriers after the hoist. Each wave owns 32 cols and sweeps all 16 32-row
// chunks; A-fragments read coalesced (wave-uniform base + lane*16) from the
// fragment-major Abfs.
__global__ __launch_bounds__(256, 2) void score_kernel(
    const short* __restrict__ Abfs, const float* __restrict__ ent,
    const float* __restrict__ ent_t, float* __restrict__ out) {
  __shared__ char lds[65536];  // B strip [128][256] bf16, swizzled

  int tid = threadIdx.x;
  int wave = tid >> 6;
  int lane = tid & 63;
  int nbase = blockIdx.x * 128;

  // ---- stage B strip: 128 rows x 256 k fp32 -> bf16, swizzled ds_write ----
#pragma unroll
  for (int i = 0; i < 32; ++i) {
    int flat = i * 256 + tid;  // 0..8191 float4 slots
    int row = flat >> 6;       // 0..127
    int c4 = flat & 63;
    int n = nbase + row;
    float4 v = make_float4(0.f, 0.f, 0.f, 0.f);
    if (n < N_ENT) {
      const float* src = (c4 < 32) ? ent + (size_t)n * 128 + c4 * 4
                                   : ent_t + (size_t)n * 128 + (c4 - 32) * 4;
      v = *(const float4*)src;
    }
    short4 bb;
    bb.x = f2bf(v.x); bb.y = f2bf(v.y); bb.z = f2bf(v.z); bb.w = f2bf(v.w);
    int chunk = c4 >> 1, half = c4 & 1;
    *(short4*)(lds + row * 512 + ((chunk ^ (row & 7)) << 4) + half * 8) = bb;
  }
  __syncthreads();  // B visible (the only barrier)

  int l31 = lane & 31, kh = lane >> 5;
  int brow = wave * 32 + l31;          // this wave's col within the strip
  int col = nbase + brow;
  bool cvalid = (col < N_ENT);         // wave-uniform (100000 % 32 == 0)

  // hoist B fragments: bfr[ks] covers k = ks*16 + kh*8 .. +7 of col `brow`
  bf16x8 bfr[16];
#pragma unroll
  for (int ks = 0; ks < 16; ++ks) {
    int c = ks * 2 + kh;
    bfr[ks] = *(const bf16x8*)(lds + brow * 512 + ((c ^ (brow & 7)) << 4));
  }

  const char* gA = (const char*)Abfs;

  for (int ci = 0; ci < 16; ++ci) {  // 16 chunks of 32 M-rows
    const char* base = gA + (size_t)(ci >> 1) * 32768 + (ci & 1) * 1024 + lane * 16;
    f32x16 acc{};
    bf16x8 af[8];
#pragma unroll
    for (int ks = 0; ks < 8; ++ks) af[ks] = *(const bf16x8*)(base + ks * 2048);
#pragma unroll
    for (int ks = 0; ks < 8; ++ks)
      acc = __builtin_amdgcn_mfma_f32_32x32x16_bf16(af[ks], bfr[ks], acc, 0, 0, 0);
#pragma unroll
    for (int ks = 0; ks < 8; ++ks) af[ks] = *(const bf16x8*)(base + (8 + ks) * 2048);
#pragma unroll
    for (int ks = 0; ks < 8; ++ks)
      acc = __builtin_amdgcn_mfma_f32_32x32x16_bf16(af[ks], bfr[8 + ks], acc, 0, 0, 0);

    if (cvalid) {
      int rbase = (ci >> 1) * 64 + (ci & 1) * 32;
#pragma unroll
      for (int r = 0; r < 16; ++r) {
        int row = rbase + (r & 3) + 8 * (r >> 2) + 4 * kh;
        float v = fminf(fmaxf(acc[r] * 0.5f, -20.0f), 20.0f);
        out[(size_t)row * N_ENT + col] = v;
      }
    }
  }
}

extern "C" void kernel_launch(void* const* d_in, const int* in_sizes, int n_in,
                              void* d_out, int out_size, void* d_ws,
                              size_t ws_size, hipStream_t stream) {
  const int* inp = (const int*)d_in[0];
  const int* nextCheckin = (const int*)d_in[1];
  const float* ctxSub = (const float*)d_in[2];
  const float* ent = (const float*)d_in[3];
  const float* ent_t = (const float*)d_in[4];
  const float* rel = (const float*)d_in[5];
  const float* rel_inv = (const float*)d_in[6];
  const float* ctx = (const float*)d_in[7];
  const float* Wqkv = (const float*)d_in[8];
  const float* bqkv = (const float*)d_in[9];
  const float* Wo = (const float*)d_in[10];
  const float* bo = (const float*)d_in[11];
  const float* W1 = (const float*)d_in[12];
  const float* b1 = (const float*)d_in[13];
  const float* W2 = (const float*)d_in[14];
  const float* b2 = (const float*)d_in[15];
  const float* g1 = (const float*)d_in[16];
  const float* be1 = (const float*)d_in[17];
  const float* g2 = (const float*)d_in[18];
  const float* be2 = (const float*)d_in[19];
  float* out = (float*)d_out;

  short* Abfs = (short*)d_ws;                         // 256 KB (fragment-major)
  short* Wbf = (short*)((char*)d_ws + 262144);        // 768 KB (fragment-major)
  float* hist = out + (size_t)NB * N_ENT;

  wbf_kernel<<<1536, 256, 0, stream>>>(Wqkv, Wo, W1, W2, Wbf);
  encoder_fused<<<NB, 256, 0, stream>>>(
      inp, nextCheckin, ctxSub, ent, ent_t, rel, rel_inv, ctx, Wbf, bqkv, bo,
      b1, b2, g1, be1, g2, be2, Abfs, hist);
  score_kernel<<<782, 256, 0, stream>>>(Abfs, ent, ent_t, out);
}

// Round 16
// 147.260 us; speedup vs baseline: 2.1200x; 1.2222x over previous
//
#include <hip/hip_runtime.h>
#include <hip/hip_bf16.h>
#include <stdint.h>

#define N_ENT 100000
#define EDIM 128
#define NHEAD 8
#define FDIM 512
#define NB 512
#define SEQ 12
#define CTXL 5
#define LN_EPS 1e-5f
#define QS 388  // qkvf row stride (floats): 384+4 pad spreads banks
#define RS 132  // rbuf row stride (floats)

typedef __attribute__((ext_vector_type(8))) short bf16x8;
typedef __attribute__((ext_vector_type(4))) float f32x4;
typedef __attribute__((ext_vector_type(16))) float f32x16;

__device__ __forceinline__ short f2bf(float f) {
  __hip_bfloat16 h = __float2bfloat16(f);
  return (short)__bfloat16_as_ushort(h);
}
__device__ __forceinline__ float bf2f(unsigned short u) {
  union { uint32_t i; float f; } x; x.i = ((uint32_t)u) << 16; return x.f;
}

// swizzled byte addr inside bf16 LDS tiles (16B chunks XOR row&7)
__device__ __forceinline__ int XADDR(int row, int k) {  // stride 256B (128 bf16)
  return row * 256 + ((((k) >> 3) ^ (row & 7)) << 4) + ((k) & 7) * 2;
}
__device__ __forceinline__ int AADDR(int row, int k) {  // stride 1024B (512 bf16)
  return row * 1024 + ((((k) >> 3) ^ (row & 7)) << 4) + ((k) & 7) * 2;
}

// ---- weights -> bf16 FRAGMENT-MAJOR layout (round-15, confirmed win) ----
#define LSTRIDE 196608
__global__ void wbf_kernel(const float* __restrict__ Wqkv,
                           const float* __restrict__ Wo,
                           const float* __restrict__ W1,
                           const float* __restrict__ W2,
                           short* __restrict__ Wbf) {
  int idx = blockIdx.x * 256 + threadIdx.x;  // 0..393215
  int layer = idx / LSTRIDE;
  int r = idx % LSTRIDE;
  float v;
  if (r < 49152) {
    int rr = r; int fid = rr >> 9; int w = rr & 511;
    int lane = w >> 3, j = w & 7, nt = fid >> 2, ks = fid & 3;
    int lr = lane & 15, q = lane >> 4;
    v = Wqkv[layer * 49152 + (nt * 16 + lr) * 128 + ks * 32 + q * 8 + j];
  } else if (r < 65536) {
    int rr = r - 49152; int fid = rr >> 9; int w = rr & 511;
    int lane = w >> 3, j = w & 7, nt = fid >> 2, ks = fid & 3;
    int lr = lane & 15, q = lane >> 4;
    v = Wo[layer * 16384 + (nt * 16 + lr) * 128 + ks * 32 + q * 8 + j];
  } else if (r < 131072) {
    int rr = r - 65536; int fid = rr >> 9; int w = rr & 511;
    int lane = w >> 3, j = w & 7, nt = fid >> 2, ks = fid & 3;
    int lr = lane & 15, q = lane >> 4;
    v = W1[layer * 65536 + (nt * 16 + lr) * 128 + ks * 32 + q * 8 + j];
  } else {
    int rr = r - 131072; int fid = rr >> 9; int w = rr & 511;
    int lane = w >> 3, j = w & 7, nt = fid >> 4, ks = fid & 15;
    int lr = lane & 15, q = lane >> 4;
    v = W2[layer * 65536 + (nt * 16 + lr) * 512 + ks * 32 + q * 8 + j];
  }
  Wbf[idx] = f2bf(v);
}

// ------- fused MFMA encoder (round-15, fragment-major weights) -------------
__global__ __launch_bounds__(256, 2) void encoder_fused(
    const int* __restrict__ inp, const int* __restrict__ nextCheckin,
    const float* __restrict__ ctxSub, const float* __restrict__ ent,
    const float* __restrict__ ent_t, const float* __restrict__ rel,
    const float* __restrict__ rel_inv, const float* __restrict__ ctx,
    const short* __restrict__ Wbf, const float* __restrict__ bqkv_,
    const float* __restrict__ bo_, const float* __restrict__ b1_,
    const float* __restrict__ b2_, const float* __restrict__ g1_,
    const float* __restrict__ be1_, const float* __restrict__ g2_,
    const float* __restrict__ be2_, short* __restrict__ Abfs,
    float* __restrict__ hist) {
  __shared__ char lds[39104];
  char* xbuf = lds;                      // [16][128] bf16 swz   4KB
  char* abuf = lds + 4096;               // [16][512] bf16 swz  16KB
  float* qkvf = (float*)(lds + 20480);   // [12][388] fp32      18.2KB
  float* rbuf = (float*)(lds + 20480);   // [12][132] fp32 (reuse)

  int m = blockIdx.x;
  int tid = threadIdx.x;
  int wave = tid >> 6, lane = tid & 63;
  int q = lane >> 4, lr = lane & 15;

  // ---- gather -> xbuf bf16 (swizzled); zero pad rows 12..15 ----
  {
    for (int i = tid; i < 256; i += 256) ((uint32_t*)(xbuf + 12 * 256))[i] = 0;
    for (int i = tid; i < 1024; i += 256) ((uint32_t*)(abuf + 12 * 1024))[i] = 0;
    if (tid < EDIM) {
      int e = tid;
      int i0 = inp[0 * NB + m], i1 = inp[1 * NB + m], i2 = inp[2 * NB + m];
      *(unsigned short*)(xbuf + XADDR(0, e)) = (unsigned short)f2bf(ent[(size_t)i0 * EDIM + e]);
      *(unsigned short*)(xbuf + XADDR(1, e)) = (unsigned short)f2bf(ent_t[(size_t)i0 * EDIM + e]);
      *(unsigned short*)(xbuf + XADDR(2, e)) = (unsigned short)f2bf(rel[(size_t)i1 * EDIM + e]);
      *(unsigned short*)(xbuf + XADDR(3, e)) = (unsigned short)f2bf(rel_inv[(size_t)i1 * EDIM + e]);
      *(unsigned short*)(xbuf + XADDR(4, e)) = (unsigned short)f2bf(ent[(size_t)i2 * EDIM + e]);
      *(unsigned short*)(xbuf + XADDR(5, e)) = (unsigned short)f2bf(ent_t[(size_t)i2 * EDIM + e]);
#pragma unroll
      for (int j = 0; j < CTXL; ++j) {
        int c = inp[(3 + j) * NB + m];
        *(unsigned short*)(xbuf + XADDR(6 + j, e)) = (unsigned short)f2bf(ctx[(size_t)c * EDIM + e]);
      }
      *(unsigned short*)(xbuf + XADDR(11, e)) = (unsigned short)f2bf(ctxSub[(size_t)m * EDIM + e]);
    }
  }
  __syncthreads();

  for (int l = 0; l < 2; ++l) {
    const short* Wq = Wbf + (size_t)l * LSTRIDE;
    const short* Wo = Wq + 49152;
    const short* W1 = Wq + 65536;
    const short* W2 = Wq + 131072;
    const float* bqkv = bqkv_ + l * 384;
    const float* bo = bo_ + l * 128;
    const float* b1 = b1_ + l * 512;
    const float* b2 = b2_ + l * 128;
    const float* g1 = g1_ + l * 128;
    const float* be1 = be1_ + l * 128;
    const float* g2 = g2_ + l * 128;
    const float* be2 = be2_ + l * 128;

    // ---------- qkv GEMM: fragment-major weight reads ----------
    {
      bf16x8 a[4];
#pragma unroll
      for (int ks = 0; ks < 4; ++ks)
        a[ks] = *(const bf16x8*)(xbuf + XADDR(lr, ks * 32 + q * 8));
      int tbase = q * 4;
      for (int nt = wave; nt < 24; nt += 4) {
        bf16x8 bq[4];
#pragma unroll
        for (int ks = 0; ks < 4; ++ks)
          bq[ks] = *(const bf16x8*)(Wq + (nt * 4 + ks) * 512 + lane * 8);
        float bias = bqkv[nt * 16 + lr];
        f32x4 acc{};
#pragma unroll
        for (int ks = 0; ks < 4; ++ks)
          acc = __builtin_amdgcn_mfma_f32_16x16x32_bf16(a[ks], bq[ks], acc, 0, 0, 0);
        if (tbase < 12) {
#pragma unroll
          for (int r = 0; r < 4; ++r)
            qkvf[(tbase + r) * QS + nt * 16 + lr] = acc[r] + bias;
        }
      }
    }
    __syncthreads();

    // ---------- attention (96 threads, fp32 from qkvf) ----------
    if (tid < 96) {
      int h = tid & 7, tq = tid >> 3;
      const float scale = 0.25f;
      float s[SEQ];
      float mx = -1e30f;
#pragma unroll
      for (int tk = 0; tk < SEQ; ++tk) {
        float d = 0.f;
#pragma unroll
        for (int dd = 0; dd < 16; ++dd)
          d += qkvf[tq * QS + h * 16 + dd] * qkvf[tk * QS + 128 + h * 16 + dd];
        s[tk] = d * scale;
        mx = fmaxf(mx, s[tk]);
      }
      float sum = 0.f;
#pragma unroll
      for (int tk = 0; tk < SEQ; ++tk) { s[tk] = __expf(s[tk] - mx); sum += s[tk]; }
      float inv = 1.0f / sum;
#pragma unroll
      for (int dd = 0; dd < 16; dd += 2) {
        float o0 = 0.f, o1 = 0.f;
#pragma unroll
        for (int tk = 0; tk < SEQ; ++tk) {
          o0 += s[tk] * qkvf[tk * QS + 256 + h * 16 + dd];
          o1 += s[tk] * qkvf[tk * QS + 256 + h * 16 + dd + 1];
        }
        uint32_t pk = (uint32_t)(unsigned short)f2bf(o0 * inv) |
                      ((uint32_t)(unsigned short)f2bf(o1 * inv) << 16);
        *(uint32_t*)(abuf + AADDR(tq, h * 16 + dd)) = pk;
      }
    }
    __syncthreads();

    // ---------- out-proj GEMM + residual -> rbuf ----------
    {
      bf16x8 a[4];
#pragma unroll
      for (int ks = 0; ks < 4; ++ks)
        a[ks] = *(const bf16x8*)(abuf + AADDR(lr, ks * 32 + q * 8));
      int tbase = q * 4;
      for (int nt = wave; nt < 8; nt += 4) {
        bf16x8 bq[4];
#pragma unroll
        for (int ks = 0; ks < 4; ++ks)
          bq[ks] = *(const bf16x8*)(Wo + (nt * 4 + ks) * 512 + lane * 8);
        float bias = bo[nt * 16 + lr];
        f32x4 acc{};
#pragma unroll
        for (int ks = 0; ks < 4; ++ks)
          acc = __builtin_amdgcn_mfma_f32_16x16x32_bf16(a[ks], bq[ks], acc, 0, 0, 0);
        if (tbase < 12) {
          int e = nt * 16 + lr;
#pragma unroll
          for (int r = 0; r < 4; ++r) {
            int t = tbase + r;
            float res = bf2f(*(const unsigned short*)(xbuf + XADDR(t, e)));
            rbuf[t * RS + e] = acc[r] + bias + res;
          }
        }
      }
    }
    __syncthreads();

    // ---------- LN1 ----------
    {
      for (int row = wave; row < SEQ; row += 4) {
        float v0 = rbuf[row * RS + 2 * lane], v1 = rbuf[row * RS + 2 * lane + 1];
        float sum = v0 + v1, sq = v0 * v0 + v1 * v1;
#pragma unroll
        for (int off = 32; off; off >>= 1) { sum += __shfl_xor(sum, off); sq += __shfl_xor(sq, off); }
        float mu = sum * (1.0f / 128.0f);
        float var = sq * (1.0f / 128.0f) - mu * mu;
        float rs = rsqrtf(var + LN_EPS);
        float y0 = (v0 - mu) * rs * g1[2 * lane] + be1[2 * lane];
        float y1 = (v1 - mu) * rs * g1[2 * lane + 1] + be1[2 * lane + 1];
        uint32_t pk = (uint32_t)(unsigned short)f2bf(y0) |
                      ((uint32_t)(unsigned short)f2bf(y1) << 16);
        *(uint32_t*)(xbuf + XADDR(row, 2 * lane)) = pk;
      }
    }
    __syncthreads();

    // ---------- FFN1 GEMM + relu -> abuf ----------
    {
      bf16x8 a[4];
#pragma unroll
      for (int ks = 0; ks < 4; ++ks)
        a[ks] = *(const bf16x8*)(xbuf + XADDR(lr, ks * 32 + q * 8));
      int tbase = q * 4;
      for (int nt = wave; nt < 32; nt += 4) {
        bf16x8 bq[4];
#pragma unroll
        for (int ks = 0; ks < 4; ++ks)
          bq[ks] = *(const bf16x8*)(W1 + (nt * 4 + ks) * 512 + lane * 8);
        float bias = b1[nt * 16 + lr];
        f32x4 acc{};
#pragma unroll
        for (int ks = 0; ks < 4; ++ks)
          acc = __builtin_amdgcn_mfma_f32_16x16x32_bf16(a[ks], bq[ks], acc, 0, 0, 0);
        if (tbase < 12) {
          int f = nt * 16 + lr;
#pragma unroll
          for (int r = 0; r < 4; ++r) {
            float h = fmaxf(acc[r] + bias, 0.0f);
            *(unsigned short*)(abuf + AADDR(tbase + r, f)) = (unsigned short)f2bf(h);
          }
        }
      }
    }
    __syncthreads();

    // ---------- FFN2 GEMM (K=512) + residual -> rbuf ----------
    {
      bf16x8 a2[16];
#pragma unroll
      for (int ks = 0; ks < 16; ++ks)
        a2[ks] = *(const bf16x8*)(abuf + AADDR(lr, ks * 32 + q * 8));
      int tbase = q * 4;
      for (int nt = wave; nt < 8; nt += 4) {
        float bias = b2[nt * 16 + lr];
        f32x4 acc{};
#pragma unroll
        for (int ks = 0; ks < 16; ++ks) {
          bf16x8 bq = *(const bf16x8*)(W2 + (nt * 16 + ks) * 512 + lane * 8);
          acc = __builtin_amdgcn_mfma_f32_16x16x32_bf16(a2[ks], bq, acc, 0, 0, 0);
        }
        if (tbase < 12) {
          int e = nt * 16 + lr;
#pragma unroll
          for (int r = 0; r < 4; ++r) {
            int t = tbase + r;
            float res = bf2f(*(const unsigned short*)(xbuf + XADDR(t, e)));
            rbuf[t * RS + e] = acc[r] + bias + res;
          }
        }
      }
    }
    __syncthreads();

    // ---------- LN2 ----------
    {
      for (int row = wave; row < SEQ; row += 4) {
        float v0 = rbuf[row * RS + 2 * lane], v1 = rbuf[row * RS + 2 * lane + 1];
        float sum = v0 + v1, sq = v0 * v0 + v1 * v1;
#pragma unroll
        for (int off = 32; off; off >>= 1) { sum += __shfl_xor(sum, off); sq += __shfl_xor(sq, off); }
        float mu = sum * (1.0f / 128.0f);
        float var = sq * (1.0f / 128.0f) - mu * mu;
        float rs = rsqrtf(var + LN_EPS);
        float y0 = (v0 - mu) * rs * g2[2 * lane] + be2[2 * lane];
        float y1 = (v1 - mu) * rs * g2[2 * lane + 1] + be2[2 * lane + 1];
        uint32_t pk = (uint32_t)(unsigned short)f2bf(y0) |
                      ((uint32_t)(unsigned short)f2bf(y1) << 16);
        *(uint32_t*)(xbuf + XADDR(row, 2 * lane)) = pk;
        rbuf[row * RS + 2 * lane] = y0;
        rbuf[row * RS + 2 * lane + 1] = y1;
      }
    }
    __syncthreads();
  }

  // ---- prep epilogue: FRAGMENT-MAJOR Abfs + hist ----
  if (tid < EDIM) {
    int e = tid;
    int r = nextCheckin[NB + m];
    float a0 = rbuf[0 * RS + e] * rel[(size_t)r * EDIM + e];
    float a1 = rbuf[1 * RS + e] * rel_inv[(size_t)r * EDIM + e];
    int mc = m >> 6, mhalf = (m >> 5) & 1, l31 = m & 31;
    int kh = (e >> 3) & 1, j = e & 7;
    int ks0 = e >> 4, ks1 = 8 + (e >> 4);
    size_t base = (size_t)mc * 16384 + (kh * 32 + l31) * 8 + j;
    Abfs[base + (ks0 * 2 + mhalf) * 512] = f2bf(a0);
    Abfs[base + (ks1 * 2 + mhalf) * 512] = f2bf(a1);
    hist[(size_t)m * EDIM + e] = rbuf[11 * RS + e];
  }
}

// ---------------- scores: ROUND-13 VERBATIM (78us proven) ------------------
// 64-col strips, 1563 blocks, 3/CU; B staged once -> bfr[16] in VGPRs; zero
// barriers after the hoist; A-fragments coalesced from fragment-major Abfs;
// 32x32 MFMA -> full 128B-line stores.
__global__ __launch_bounds__(256, 3) void score_kernel(
    const short* __restrict__ Abfs, const float* __restrict__ ent,
    const float* __restrict__ ent_t, float* __restrict__ out) {
  __shared__ char lds[32768];  // B strip only

  int tid = threadIdx.x;
  int wave = tid >> 6;
  int lane = tid & 63;
  int nbase = blockIdx.x * 64;

#pragma unroll
  for (int i = 0; i < 16; ++i) {
    int flat = i * 256 + tid;
    int row = flat >> 6;
    int c4 = flat & 63;
    int n = nbase + row;
    float4 v = make_float4(0.f, 0.f, 0.f, 0.f);
    if (n < N_ENT) {
      const float* src = (c4 < 32) ? ent + (size_t)n * 128 + c4 * 4
                                   : ent_t + (size_t)n * 128 + (c4 - 32) * 4;
      v = *(const float4*)src;
    }
    short4 bb;
    bb.x = f2bf(v.x); bb.y = f2bf(v.y); bb.z = f2bf(v.z); bb.w = f2bf(v.w);
    int chunk = c4 >> 1, half = c4 & 1;
    *(short4*)(lds + row * 512 + ((chunk ^ (row & 7)) << 4) + half * 8) = bb;
  }
  __syncthreads();  // B visible (the only barrier)

  int l31 = lane & 31, kh = lane >> 5;
  int nhalf = wave >> 1, mhalf = wave & 1;
  int brow = nhalf * 32 + l31;
  int col = nbase + nhalf * 32 + l31;
  bool cvalid = (col < N_ENT);

  bf16x8 bfr[16];
#pragma unroll
  for (int ks = 0; ks < 16; ++ks) {
    int c = ks * 2 + kh;
    bfr[ks] = *(const bf16x8*)(lds + brow * 512 + ((c ^ (brow & 7)) << 4));
  }

  const char* gA = (const char*)Abfs;

  for (int mc = 0; mc < 8; ++mc) {
    const char* base = gA + (size_t)mc * 32768 + mhalf * 1024 + lane * 16;
    f32x16 acc{};
    bf16x8 af[8];
#pragma unroll
    for (int ks = 0; ks < 8; ++ks) af[ks] = *(const bf16x8*)(base + ks * 2048);
#pragma unroll
    for (int ks = 0; ks < 8; ++ks)
      acc = __builtin_amdgcn_mfma_f32_32x32x16_bf16(af[ks], bfr[ks], acc, 0, 0, 0);
#pragma unroll
    for (int ks = 0; ks < 8; ++ks) af[ks] = *(const bf16x8*)(base + (8 + ks) * 2048);
#pragma unroll
    for (int ks = 0; ks < 8; ++ks)
      acc = __builtin_amdgcn_mfma_f32_32x32x16_bf16(af[ks], bfr[8 + ks], acc, 0, 0, 0);

    if (cvalid) {
#pragma unroll
      for (int r = 0; r < 16; ++r) {
        int row = mc * 64 + mhalf * 32 + (r & 3) + 8 * (r >> 2) + 4 * kh;
        float v = fminf(fmaxf(acc[r] * 0.5f, -20.0f), 20.0f);
        out[(size_t)row * N_ENT + col] = v;
      }
    }
  }
}

extern "C" void kernel_launch(void* const* d_in, const int* in_sizes, int n_in,
                              void* d_out, int out_size, void* d_ws,
                              size_t ws_size, hipStream_t stream) {
  const int* inp = (const int*)d_in[0];
  const int* nextCheckin = (const int*)d_in[1];
  const float* ctxSub = (const float*)d_in[2];
  const float* ent = (const float*)d_in[3];
  const float* ent_t = (const float*)d_in[4];
  const float* rel = (const float*)d_in[5];
  const float* rel_inv = (const float*)d_in[6];
  const float* ctx = (const float*)d_in[7];
  const float* Wqkv = (const float*)d_in[8];
  const float* bqkv = (const float*)d_in[9];
  const float* Wo = (const float*)d_in[10];
  const float* bo = (const float*)d_in[11];
  const float* W1 = (const float*)d_in[12];
  const float* b1 = (const float*)d_in[13];
  const float* W2 = (const float*)d_in[14];
  const float* b2 = (const float*)d_in[15];
  const float* g1 = (const float*)d_in[16];
  const float* be1 = (const float*)d_in[17];
  const float* g2 = (const float*)d_in[18];
  const float* be2 = (const float*)d_in[19];
  float* out = (float*)d_out;

  short* Abfs = (short*)d_ws;                         // 256 KB (fragment-major)
  short* Wbf = (short*)((char*)d_ws + 262144);        // 768 KB (fragment-major)
  float* hist = out + (size_t)NB * N_ENT;

  wbf_kernel<<<1536, 256, 0, stream>>>(Wqkv, Wo, W1, W2, Wbf);
  encoder_fused<<<NB, 256, 0, stream>>>(
      inp, nextCheckin, ctxSub, ent, ent_t, rel, rel_inv, ctx, Wbf, bqkv, bo,
      b1, b2, g1, be1, g2, be2, Abfs, hist);
  score_kernel<<<1563, 256, 0, stream>>>(Abfs, ent, ent_t, out);
}

// Round 17
// 132.347 us; speedup vs baseline: 2.3589x; 1.1127x over previous
//
#include <hip/hip_runtime.h>
#include <hip/hip_bf16.h>
#include <stdint.h>

#define N_ENT 100000
#define EDIM 128
#define NHEAD 8
#define FDIM 512
#define NB 512
#define SEQ 12
#define CTXL 5
#define LN_EPS 1e-5f
#define QS 388  // qkvf row stride (floats): 384+4 pad spreads banks
#define RS 132  // rbuf row stride (floats)

typedef __attribute__((ext_vector_type(8))) short bf16x8;
typedef __attribute__((ext_vector_type(4))) float f32x4;
typedef __attribute__((ext_vector_type(16))) float f32x16;

__device__ __forceinline__ short f2bf(float f) {
  __hip_bfloat16 h = __float2bfloat16(f);
  return (short)__bfloat16_as_ushort(h);
}
__device__ __forceinline__ float bf2f(unsigned short u) {
  union { uint32_t i; float f; } x; x.i = ((uint32_t)u) << 16; return x.f;
}

// swizzled byte addr inside bf16 LDS tiles (16B chunks XOR row&7)
__device__ __forceinline__ int XADDR(int row, int k) {  // stride 256B (128 bf16)
  return row * 256 + ((((k) >> 3) ^ (row & 7)) << 4) + ((k) & 7) * 2;
}
__device__ __forceinline__ int AADDR(int row, int k) {  // stride 1024B (512 bf16)
  return row * 1024 + ((((k) >> 3) ^ (row & 7)) << 4) + ((k) & 7) * 2;
}

// ---- weights -> bf16 FRAGMENT-MAJOR layout (round-15, confirmed win) ----
#define LSTRIDE 196608
__global__ void wbf_kernel(const float* __restrict__ Wqkv,
                           const float* __restrict__ Wo,
                           const float* __restrict__ W1,
                           const float* __restrict__ W2,
                           short* __restrict__ Wbf) {
  int idx = blockIdx.x * 256 + threadIdx.x;  // 0..393215
  int layer = idx / LSTRIDE;
  int r = idx % LSTRIDE;
  float v;
  if (r < 49152) {
    int rr = r; int fid = rr >> 9; int w = rr & 511;
    int lane = w >> 3, j = w & 7, nt = fid >> 2, ks = fid & 3;
    int lr = lane & 15, q = lane >> 4;
    v = Wqkv[layer * 49152 + (nt * 16 + lr) * 128 + ks * 32 + q * 8 + j];
  } else if (r < 65536) {
    int rr = r - 49152; int fid = rr >> 9; int w = rr & 511;
    int lane = w >> 3, j = w & 7, nt = fid >> 2, ks = fid & 3;
    int lr = lane & 15, q = lane >> 4;
    v = Wo[layer * 16384 + (nt * 16 + lr) * 128 + ks * 32 + q * 8 + j];
  } else if (r < 131072) {
    int rr = r - 65536; int fid = rr >> 9; int w = rr & 511;
    int lane = w >> 3, j = w & 7, nt = fid >> 2, ks = fid & 3;
    int lr = lane & 15, q = lane >> 4;
    v = W1[layer * 65536 + (nt * 16 + lr) * 128 + ks * 32 + q * 8 + j];
  } else {
    int rr = r - 131072; int fid = rr >> 9; int w = rr & 511;
    int lane = w >> 3, j = w & 7, nt = fid >> 4, ks = fid & 15;
    int lr = lane & 15, q = lane >> 4;
    v = W2[layer * 65536 + (nt * 16 + lr) * 512 + ks * 32 + q * 8 + j];
  }
  Wbf[idx] = f2bf(v);
}

// ------- fused MFMA encoder (round-15/16, fragment-major weights) ----------
__global__ __launch_bounds__(256, 2) void encoder_fused(
    const int* __restrict__ inp, const int* __restrict__ nextCheckin,
    const float* __restrict__ ctxSub, const float* __restrict__ ent,
    const float* __restrict__ ent_t, const float* __restrict__ rel,
    const float* __restrict__ rel_inv, const float* __restrict__ ctx,
    const short* __restrict__ Wbf, const float* __restrict__ bqkv_,
    const float* __restrict__ bo_, const float* __restrict__ b1_,
    const float* __restrict__ b2_, const float* __restrict__ g1_,
    const float* __restrict__ be1_, const float* __restrict__ g2_,
    const float* __restrict__ be2_, short* __restrict__ Abfs,
    float* __restrict__ hist) {
  __shared__ char lds[39104];
  char* xbuf = lds;                      // [16][128] bf16 swz   4KB
  char* abuf = lds + 4096;               // [16][512] bf16 swz  16KB
  float* qkvf = (float*)(lds + 20480);   // [12][388] fp32      18.2KB
  float* rbuf = (float*)(lds + 20480);   // [12][132] fp32 (reuse)

  int m = blockIdx.x;
  int tid = threadIdx.x;
  int wave = tid >> 6, lane = tid & 63;
  int q = lane >> 4, lr = lane & 15;

  // ---- gather -> xbuf bf16 (swizzled); zero pad rows 12..15 ----
  {
    for (int i = tid; i < 256; i += 256) ((uint32_t*)(xbuf + 12 * 256))[i] = 0;
    for (int i = tid; i < 1024; i += 256) ((uint32_t*)(abuf + 12 * 1024))[i] = 0;
    if (tid < EDIM) {
      int e = tid;
      int i0 = inp[0 * NB + m], i1 = inp[1 * NB + m], i2 = inp[2 * NB + m];
      *(unsigned short*)(xbuf + XADDR(0, e)) = (unsigned short)f2bf(ent[(size_t)i0 * EDIM + e]);
      *(unsigned short*)(xbuf + XADDR(1, e)) = (unsigned short)f2bf(ent_t[(size_t)i0 * EDIM + e]);
      *(unsigned short*)(xbuf + XADDR(2, e)) = (unsigned short)f2bf(rel[(size_t)i1 * EDIM + e]);
      *(unsigned short*)(xbuf + XADDR(3, e)) = (unsigned short)f2bf(rel_inv[(size_t)i1 * EDIM + e]);
      *(unsigned short*)(xbuf + XADDR(4, e)) = (unsigned short)f2bf(ent[(size_t)i2 * EDIM + e]);
      *(unsigned short*)(xbuf + XADDR(5, e)) = (unsigned short)f2bf(ent_t[(size_t)i2 * EDIM + e]);
#pragma unroll
      for (int j = 0; j < CTXL; ++j) {
        int c = inp[(3 + j) * NB + m];
        *(unsigned short*)(xbuf + XADDR(6 + j, e)) = (unsigned short)f2bf(ctx[(size_t)c * EDIM + e]);
      }
      *(unsigned short*)(xbuf + XADDR(11, e)) = (unsigned short)f2bf(ctxSub[(size_t)m * EDIM + e]);
    }
  }
  __syncthreads();

  for (int l = 0; l < 2; ++l) {
    const short* Wq = Wbf + (size_t)l * LSTRIDE;
    const short* Wo = Wq + 49152;
    const short* W1 = Wq + 65536;
    const short* W2 = Wq + 131072;
    const float* bqkv = bqkv_ + l * 384;
    const float* bo = bo_ + l * 128;
    const float* b1 = b1_ + l * 512;
    const float* b2 = b2_ + l * 128;
    const float* g1 = g1_ + l * 128;
    const float* be1 = be1_ + l * 128;
    const float* g2 = g2_ + l * 128;
    const float* be2 = be2_ + l * 128;

    // ---------- qkv GEMM: fragment-major weight reads ----------
    {
      bf16x8 a[4];
#pragma unroll
      for (int ks = 0; ks < 4; ++ks)
        a[ks] = *(const bf16x8*)(xbuf + XADDR(lr, ks * 32 + q * 8));
      int tbase = q * 4;
      for (int nt = wave; nt < 24; nt += 4) {
        bf16x8 bq[4];
#pragma unroll
        for (int ks = 0; ks < 4; ++ks)
          bq[ks] = *(const bf16x8*)(Wq + (nt * 4 + ks) * 512 + lane * 8);
        float bias = bqkv[nt * 16 + lr];
        f32x4 acc{};
#pragma unroll
        for (int ks = 0; ks < 4; ++ks)
          acc = __builtin_amdgcn_mfma_f32_16x16x32_bf16(a[ks], bq[ks], acc, 0, 0, 0);
        if (tbase < 12) {
#pragma unroll
          for (int r = 0; r < 4; ++r)
            qkvf[(tbase + r) * QS + nt * 16 + lr] = acc[r] + bias;
        }
      }
    }
    __syncthreads();

    // ---------- attention (96 threads, fp32 from qkvf) ----------
    if (tid < 96) {
      int h = tid & 7, tq = tid >> 3;
      const float scale = 0.25f;
      float s[SEQ];
      float mx = -1e30f;
#pragma unroll
      for (int tk = 0; tk < SEQ; ++tk) {
        float d = 0.f;
#pragma unroll
        for (int dd = 0; dd < 16; ++dd)
          d += qkvf[tq * QS + h * 16 + dd] * qkvf[tk * QS + 128 + h * 16 + dd];
        s[tk] = d * scale;
        mx = fmaxf(mx, s[tk]);
      }
      float sum = 0.f;
#pragma unroll
      for (int tk = 0; tk < SEQ; ++tk) { s[tk] = __expf(s[tk] - mx); sum += s[tk]; }
      float inv = 1.0f / sum;
#pragma unroll
      for (int dd = 0; dd < 16; dd += 2) {
        float o0 = 0.f, o1 = 0.f;
#pragma unroll
        for (int tk = 0; tk < SEQ; ++tk) {
          o0 += s[tk] * qkvf[tk * QS + 256 + h * 16 + dd];
          o1 += s[tk] * qkvf[tk * QS + 256 + h * 16 + dd + 1];
        }
        uint32_t pk = (uint32_t)(unsigned short)f2bf(o0 * inv) |
                      ((uint32_t)(unsigned short)f2bf(o1 * inv) << 16);
        *(uint32_t*)(abuf + AADDR(tq, h * 16 + dd)) = pk;
      }
    }
    __syncthreads();

    // ---------- out-proj GEMM + residual -> rbuf ----------
    {
      bf16x8 a[4];
#pragma unroll
      for (int ks = 0; ks < 4; ++ks)
        a[ks] = *(const bf16x8*)(abuf + AADDR(lr, ks * 32 + q * 8));
      int tbase = q * 4;
      for (int nt = wave; nt < 8; nt += 4) {
        bf16x8 bq[4];
#pragma unroll
        for (int ks = 0; ks < 4; ++ks)
          bq[ks] = *(const bf16x8*)(Wo + (nt * 4 + ks) * 512 + lane * 8);
        float bias = bo[nt * 16 + lr];
        f32x4 acc{};
#pragma unroll
        for (int ks = 0; ks < 4; ++ks)
          acc = __builtin_amdgcn_mfma_f32_16x16x32_bf16(a[ks], bq[ks], acc, 0, 0, 0);
        if (tbase < 12) {
          int e = nt * 16 + lr;
#pragma unroll
          for (int r = 0; r < 4; ++r) {
            int t = tbase + r;
            float res = bf2f(*(const unsigned short*)(xbuf + XADDR(t, e)));
            rbuf[t * RS + e] = acc[r] + bias + res;
          }
        }
      }
    }
    __syncthreads();

    // ---------- LN1 ----------
    {
      for (int row = wave; row < SEQ; row += 4) {
        float v0 = rbuf[row * RS + 2 * lane], v1 = rbuf[row * RS + 2 * lane + 1];
        float sum = v0 + v1, sq = v0 * v0 + v1 * v1;
#pragma unroll
        for (int off = 32; off; off >>= 1) { sum += __shfl_xor(sum, off); sq += __shfl_xor(sq, off); }
        float mu = sum * (1.0f / 128.0f);
        float var = sq * (1.0f / 128.0f) - mu * mu;
        float rs = rsqrtf(var + LN_EPS);
        float y0 = (v0 - mu) * rs * g1[2 * lane] + be1[2 * lane];
        float y1 = (v1 - mu) * rs * g1[2 * lane + 1] + be1[2 * lane + 1];
        uint32_t pk = (uint32_t)(unsigned short)f2bf(y0) |
                      ((uint32_t)(unsigned short)f2bf(y1) << 16);
        *(uint32_t*)(xbuf + XADDR(row, 2 * lane)) = pk;
      }
    }
    __syncthreads();

    // ---------- FFN1 GEMM + relu -> abuf ----------
    {
      bf16x8 a[4];
#pragma unroll
      for (int ks = 0; ks < 4; ++ks)
        a[ks] = *(const bf16x8*)(xbuf + XADDR(lr, ks * 32 + q * 8));
      int tbase = q * 4;
      for (int nt = wave; nt < 32; nt += 4) {
        bf16x8 bq[4];
#pragma unroll
        for (int ks = 0; ks < 4; ++ks)
          bq[ks] = *(const bf16x8*)(W1 + (nt * 4 + ks) * 512 + lane * 8);
        float bias = b1[nt * 16 + lr];
        f32x4 acc{};
#pragma unroll
        for (int ks = 0; ks < 4; ++ks)
          acc = __builtin_amdgcn_mfma_f32_16x16x32_bf16(a[ks], bq[ks], acc, 0, 0, 0);
        if (tbase < 12) {
          int f = nt * 16 + lr;
#pragma unroll
          for (int r = 0; r < 4; ++r) {
            float h = fmaxf(acc[r] + bias, 0.0f);
            *(unsigned short*)(abuf + AADDR(tbase + r, f)) = (unsigned short)f2bf(h);
          }
        }
      }
    }
    __syncthreads();

    // ---------- FFN2 GEMM (K=512) + residual -> rbuf ----------
    {
      bf16x8 a2[16];
#pragma unroll
      for (int ks = 0; ks < 16; ++ks)
        a2[ks] = *(const bf16x8*)(abuf + AADDR(lr, ks * 32 + q * 8));
      int tbase = q * 4;
      for (int nt = wave; nt < 8; nt += 4) {
        float bias = b2[nt * 16 + lr];
        f32x4 acc{};
#pragma unroll
        for (int ks = 0; ks < 16; ++ks) {
          bf16x8 bq = *(const bf16x8*)(W2 + (nt * 16 + ks) * 512 + lane * 8);
          acc = __builtin_amdgcn_mfma_f32_16x16x32_bf16(a2[ks], bq, acc, 0, 0, 0);
        }
        if (tbase < 12) {
          int e = nt * 16 + lr;
#pragma unroll
          for (int r = 0; r < 4; ++r) {
            int t = tbase + r;
            float res = bf2f(*(const unsigned short*)(xbuf + XADDR(t, e)));
            rbuf[t * RS + e] = acc[r] + bias + res;
          }
        }
      }
    }
    __syncthreads();

    // ---------- LN2 ----------
    {
      for (int row = wave; row < SEQ; row += 4) {
        float v0 = rbuf[row * RS + 2 * lane], v1 = rbuf[row * RS + 2 * lane + 1];
        float sum = v0 + v1, sq = v0 * v0 + v1 * v1;
#pragma unroll
        for (int off = 32; off; off >>= 1) { sum += __shfl_xor(sum, off); sq += __shfl_xor(sq, off); }
        float mu = sum * (1.0f / 128.0f);
        float var = sq * (1.0f / 128.0f) - mu * mu;
        float rs = rsqrtf(var + LN_EPS);
        float y0 = (v0 - mu) * rs * g2[2 * lane] + be2[2 * lane];
        float y1 = (v1 - mu) * rs * g2[2 * lane + 1] + be2[2 * lane + 1];
        uint32_t pk = (uint32_t)(unsigned short)f2bf(y0) |
                      ((uint32_t)(unsigned short)f2bf(y1) << 16);
        *(uint32_t*)(xbuf + XADDR(row, 2 * lane)) = pk;
        rbuf[row * RS + 2 * lane] = y0;
        rbuf[row * RS + 2 * lane + 1] = y1;
      }
    }
    __syncthreads();
  }

  // ---- prep epilogue: FRAGMENT-MAJOR Abfs + hist ----
  if (tid < EDIM) {
    int e = tid;
    int r = nextCheckin[NB + m];
    float a0 = rbuf[0 * RS + e] * rel[(size_t)r * EDIM + e];
    float a1 = rbuf[1 * RS + e] * rel_inv[(size_t)r * EDIM + e];
    int mc = m >> 6, mhalf = (m >> 5) & 1, l31 = m & 31;
    int kh = (e >> 3) & 1, j = e & 7;
    int ks0 = e >> 4, ks1 = 8 + (e >> 4);
    size_t base = (size_t)mc * 16384 + (kh * 32 + l31) * 8 + j;
    Abfs[base + (ks0 * 2 + mhalf) * 512] = f2bf(a0);
    Abfs[base + (ks1 * 2 + mhalf) * 512] = f2bf(a1);
    hist[(size_t)m * EDIM + e] = rbuf[11 * RS + e];
  }
}

// ---------------- scores: round-13 structure + NT stores + XCD swizzle -----
// Write-path experiment: (1) __builtin_nontemporal_store for all out-writes
// (bypass L2 write-allocate -> program-order store stream, no random dirty-
// line evictions); (2) bijective XCD-chunked strip remap (1563 = 8*195+3) so
// adjacent 256B row-segments are produced on the same XCD/L2/channel path.
__global__ __launch_bounds__(256, 3) void score_kernel(
    const short* __restrict__ Abfs, const float* __restrict__ ent,
    const float* __restrict__ ent_t, float* __restrict__ out) {
  __shared__ char lds[32768];  // B strip only

  int tid = threadIdx.x;
  int wave = tid >> 6;
  int lane = tid & 63;

  // bijective XCD-chunk remap: xcd = bid%8 owns a contiguous strip range
  int bid = blockIdx.x;
  int xcd = bid & 7, idx = bid >> 3;
  const int qq = 195, rr = 3;  // 1563 = 8*195 + 3
  int strip = (xcd < rr) ? (xcd * (qq + 1) + idx)
                         : (rr * (qq + 1) + (xcd - rr) * qq + idx);
  int nbase = strip * 64;

#pragma unroll
  for (int i = 0; i < 16; ++i) {
    int flat = i * 256 + tid;
    int row = flat >> 6;
    int c4 = flat & 63;
    int n = nbase + row;
    float4 v = make_float4(0.f, 0.f, 0.f, 0.f);
    if (n < N_ENT) {
      const float* src = (c4 < 32) ? ent + (size_t)n * 128 + c4 * 4
                                   : ent_t + (size_t)n * 128 + (c4 - 32) * 4;
      v = *(const float4*)src;
    }
    short4 bb;
    bb.x = f2bf(v.x); bb.y = f2bf(v.y); bb.z = f2bf(v.z); bb.w = f2bf(v.w);
    int chunk = c4 >> 1, half = c4 & 1;
    *(short4*)(lds + row * 512 + ((chunk ^ (row & 7)) << 4) + half * 8) = bb;
  }
  __syncthreads();  // B visible (the only barrier)

  int l31 = lane & 31, kh = lane >> 5;
  int nhalf = wave >> 1, mhalf = wave & 1;
  int brow = nhalf * 32 + l31;
  int col = nbase + nhalf * 32 + l31;
  bool cvalid = (col < N_ENT);

  bf16x8 bfr[16];
#pragma unroll
  for (int ks = 0; ks < 16; ++ks) {
    int c = ks * 2 + kh;
    bfr[ks] = *(const bf16x8*)(lds + brow * 512 + ((c ^ (brow & 7)) << 4));
  }

  const char* gA = (const char*)Abfs;

  for (int mc = 0; mc < 8; ++mc) {
    const char* base = gA + (size_t)mc * 32768 + mhalf * 1024 + lane * 16;
    f32x16 acc{};
    bf16x8 af[8];
#pragma unroll
    for (int ks = 0; ks < 8; ++ks) af[ks] = *(const bf16x8*)(base + ks * 2048);
#pragma unroll
    for (int ks = 0; ks < 8; ++ks)
      acc = __builtin_amdgcn_mfma_f32_32x32x16_bf16(af[ks], bfr[ks], acc, 0, 0, 0);
#pragma unroll
    for (int ks = 0; ks < 8; ++ks) af[ks] = *(const bf16x8*)(base + (8 + ks) * 2048);
#pragma unroll
    for (int ks = 0; ks < 8; ++ks)
      acc = __builtin_amdgcn_mfma_f32_32x32x16_bf16(af[ks], bfr[8 + ks], acc, 0, 0, 0);

    if (cvalid) {
#pragma unroll
      for (int r = 0; r < 16; ++r) {
        int row = mc * 64 + mhalf * 32 + (r & 3) + 8 * (r >> 2) + 4 * kh;
        float v = fminf(fmaxf(acc[r] * 0.5f, -20.0f), 20.0f);
        __builtin_nontemporal_store(v, &out[(size_t)row * N_ENT + col]);
      }
    }
  }
}

extern "C" void kernel_launch(void* const* d_in, const int* in_sizes, int n_in,
                              void* d_out, int out_size, void* d_ws,
                              size_t ws_size, hipStream_t stream) {
  const int* inp = (const int*)d_in[0];
  const int* nextCheckin = (const int*)d_in[1];
  const float* ctxSub = (const float*)d_in[2];
  const float* ent = (const float*)d_in[3];
  const float* ent_t = (const float*)d_in[4];
  const float* rel = (const float*)d_in[5];
  const float* rel_inv = (const float*)d_in[6];
  const float* ctx = (const float*)d_in[7];
  const float* Wqkv = (const float*)d_in[8];
  const float* bqkv = (const float*)d_in[9];
  const float* Wo = (const float*)d_in[10];
  const float* bo = (const float*)d_in[11];
  const float* W1 = (const float*)d_in[12];
  const float* b1 = (const float*)d_in[13];
  const float* W2 = (const float*)d_in[14];
  const float* b2 = (const float*)d_in[15];
  const float* g1 = (const float*)d_in[16];
  const float* be1 = (const float*)d_in[17];
  const float* g2 = (const float*)d_in[18];
  const float* be2 = (const float*)d_in[19];
  float* out = (float*)d_out;

  short* Abfs = (short*)d_ws;                         // 256 KB (fragment-major)
  short* Wbf = (short*)((char*)d_ws + 262144);        // 768 KB (fragment-major)
  float* hist = out + (size_t)NB * N_ENT;

  wbf_kernel<<<1536, 256, 0, stream>>>(Wqkv, Wo, W1, W2, Wbf);
  encoder_fused<<<NB, 256, 0, stream>>>(
      inp, nextCheckin, ctxSub, ent, ent_t, rel, rel_inv, ctx, Wbf, bqkv, bo,
      b1, b2, g1, be1, g2, be2, Abfs, hist);
  score_kernel<<<1563, 256, 0, stream>>>(Abfs, ent, ent_t, out);
}